// Round 1
// baseline (153.119 us; speedup 1.0000x reference)
//
#include <hip/hip_runtime.h>

#define NB 16          // batch
#define NH 512
#define NW 512

// db2 decomposition filters
__device__ __constant__ float DLO[4] = {-0.12940952255092145f, 0.22414386804185735f, 0.836516303737469f, 0.48296291314469025f};
__device__ __constant__ float DHI[4] = {-0.48296291314469025f, 0.836516303737469f, -0.22414386804185735f, -0.12940952255092145f};

__device__ inline void block_amax_atomic(float v_abs, float* red, unsigned int* dst) {
    int tid = threadIdx.x;
    red[tid] = v_abs;
    __syncthreads();
    #pragma unroll
    for (int s = 128; s > 0; s >>= 1) {
        if (tid < s) red[tid] = fmaxf(red[tid], red[tid + s]);
        __syncthreads();
    }
    if (tid == 0) atomicMax(dst, __float_as_uint(red[0]));
    __syncthreads();
}

// Level-1 DWT: x (512x512) -> a1 (256x256, scratch), ad1/da1/dd1 raw into arr_raw quadrants.
__global__ __launch_bounds__(256) void k_dwt1(const float* __restrict__ x,
                                              float* __restrict__ arr_raw,
                                              float* __restrict__ a1,
                                              unsigned int* __restrict__ maxbuf) {
    int b = blockIdx.y;
    int idx = blockIdx.x * 256 + threadIdx.x;
    int r = idx >> 8, c = idx & 255;
    const float* xb = x + (size_t)b * (NH * NW);

    float lo[4], hi[4];
    #pragma unroll
    for (int l = 0; l < 4; ++l) {
        int cc = (2 * c + 1 - l + 512) & 511;
        float alo = 0.f, ahi = 0.f;
        #pragma unroll
        for (int k = 0; k < 4; ++k) {
            int rr = (2 * r + 1 - k + 512) & 511;
            float v = xb[rr * 512 + cc];
            alo += DLO[k] * v;
            ahi += DHI[k] * v;
        }
        lo[l] = alo; hi[l] = ahi;
    }
    float va = 0.f, vad = 0.f, vda = 0.f, vdd = 0.f;
    #pragma unroll
    for (int l = 0; l < 4; ++l) {
        va  += DLO[l] * lo[l];
        vad += DHI[l] * lo[l];
        vda += DLO[l] * hi[l];
        vdd += DHI[l] * hi[l];
    }

    a1[b * 65536 + r * 256 + c] = va;
    float* arr = arr_raw + (size_t)b * (512 * 512);
    arr[r * 512 + (c + 256)]         = vad;  // top-right
    arr[(r + 256) * 512 + c]         = vda;  // bottom-left
    arr[(r + 256) * 512 + (c + 256)] = vdd;  // bottom-right

    __shared__ float red[256];
    unsigned int* mb = maxbuf + b * 8;
    block_amax_atomic(fabsf(vad), red, mb + 0);
    block_amax_atomic(fabsf(vda), red, mb + 1);
    block_amax_atomic(fabsf(vdd), red, mb + 2);
}

// Level-2 DWT: a1 (256x256) -> a2 raw (top-left 128x128 of arr_raw + scratch), ad2/da2/dd2 raw.
__global__ __launch_bounds__(256) void k_dwt2(const float* __restrict__ a1,
                                              float* __restrict__ arr_raw,
                                              float* __restrict__ a2,
                                              unsigned int* __restrict__ maxbuf) {
    int b = blockIdx.y;
    int idx = blockIdx.x * 256 + threadIdx.x;
    int r = idx >> 7, c = idx & 127;
    const float* ab = a1 + b * 65536;

    float lo[4], hi[4];
    #pragma unroll
    for (int l = 0; l < 4; ++l) {
        int cc = (2 * c + 1 - l + 256) & 255;
        float alo = 0.f, ahi = 0.f;
        #pragma unroll
        for (int k = 0; k < 4; ++k) {
            int rr = (2 * r + 1 - k + 256) & 255;
            float v = ab[rr * 256 + cc];
            alo += DLO[k] * v;
            ahi += DHI[k] * v;
        }
        lo[l] = alo; hi[l] = ahi;
    }
    float va = 0.f, vad = 0.f, vda = 0.f, vdd = 0.f;
    #pragma unroll
    for (int l = 0; l < 4; ++l) {
        va  += DLO[l] * lo[l];
        vad += DHI[l] * lo[l];
        vda += DLO[l] * hi[l];
        vdd += DHI[l] * hi[l];
    }

    a2[b * 16384 + r * 128 + c] = va;
    float* arr = arr_raw + (size_t)b * (512 * 512);
    arr[r * 512 + c]                 = va;   // raw a2 in final position
    arr[r * 512 + (c + 128)]         = vad;
    arr[(r + 128) * 512 + c]         = vda;
    arr[(r + 128) * 512 + (c + 128)] = vdd;

    __shared__ float red[256];
    unsigned int* mb = maxbuf + b * 8;
    block_amax_atomic(fabsf(va),  red, mb + 3);
    block_amax_atomic(fabsf(vad), red, mb + 4);
    block_amax_atomic(fabsf(vda), red, mb + 5);
    block_amax_atomic(fabsf(vdd), red, mb + 6);
}

// Fused: normalize+assemble (ch0), bilinear low branch (ch1), 3x3 conv 2->16, +bias.
// Tile: 64 wide x 16 high per block of 256 threads; each thread does 4 rows x 1 col.
__global__ __launch_bounds__(256) void k_conv(const float* __restrict__ arr_raw,
                                              const float* __restrict__ a2,
                                              const unsigned int* __restrict__ maxbuf,
                                              const float* __restrict__ hfw,
                                              const float* __restrict__ lfw,
                                              const float* __restrict__ cw,
                                              const float* __restrict__ cb,
                                              float* __restrict__ out) {
    int b   = blockIdx.z;
    int th0 = blockIdx.y * 16;
    int tw0 = blockIdx.x * 64;
    int tid = threadIdx.x;

    __shared__ float ws[304];               // 288 conv weights + 16 bias
    __shared__ float tile[2][18][66];

    for (int i = tid; i < 304; i += 256) ws[i] = (i < 288) ? cw[i] : cb[i - 288];

    const unsigned int* mb = maxbuf + b * 8;
    float inv_ad1 = 1.f / __uint_as_float(mb[0]);
    float inv_da1 = 1.f / __uint_as_float(mb[1]);
    float inv_dd1 = 1.f / __uint_as_float(mb[2]);
    float inv_a2  = 1.f / __uint_as_float(mb[3]);
    float inv_ad2 = 1.f / __uint_as_float(mb[4]);
    float inv_da2 = 1.f / __uint_as_float(mb[5]);
    float inv_dd2 = 1.f / __uint_as_float(mb[6]);

    const float* arr = arr_raw + (size_t)b * (512 * 512);
    const float* a2b = a2 + b * 16384;

    for (int i = tid; i < 18 * 66; i += 256) {
        int row = i / 66;
        int col = i - row * 66;
        int gh = th0 + row - 1;
        int gw = tw0 + col - 1;
        float v0 = 0.f, v1 = 0.f;
        if (gh >= 0 && gh < 512 && gw >= 0 && gw < 512) {
            // channel 0: normalized quad-tree * hfw
            float raw = arr[gh * 512 + gw];
            float inv;
            if (gh < 256) {
                if (gw < 256) {
                    if (gh < 128) inv = (gw < 128) ? inv_a2 : inv_ad2;
                    else          inv = (gw < 128) ? inv_da2 : inv_dd2;
                } else inv = inv_ad1;
            } else inv = (gw < 256) ? inv_da1 : inv_dd1;
            v0 = raw * inv * hfw[gh * 512 + gw];

            // channel 1: bilinear upsample of norm(a2)*lfw (half-pixel, clip)
            float sh = fminf(fmaxf(0.25f * (float)gh - 0.375f, 0.f), 127.f);
            float sw = fminf(fmaxf(0.25f * (float)gw - 0.375f, 0.f), 127.f);
            int r0 = (int)sh; float fr = sh - (float)r0; int r1 = min(r0 + 1, 127);
            int c0 = (int)sw; float fc = sw - (float)c0; int c1 = min(c0 + 1, 127);
            float g00 = a2b[r0 * 128 + c0] * inv_a2 * lfw[r0 * 128 + c0];
            float g01 = a2b[r0 * 128 + c1] * inv_a2 * lfw[r0 * 128 + c1];
            float g10 = a2b[r1 * 128 + c0] * inv_a2 * lfw[r1 * 128 + c0];
            float g11 = a2b[r1 * 128 + c1] * inv_a2 * lfw[r1 * 128 + c1];
            float t0 = g00 * (1.f - fr) + g10 * fr;   // rows first (matches ref order)
            float t1 = g01 * (1.f - fr) + g11 * fr;
            v1 = t0 * (1.f - fc) + t1 * fc;
        }
        tile[0][row][col] = v0;
        tile[1][row][col] = v1;
    }
    __syncthreads();

    int lx  = tid & 63;
    int ly0 = (tid >> 6) << 2;   // 0,4,8,12

    float acc[4][16];
    #pragma unroll
    for (int p = 0; p < 4; ++p)
        #pragma unroll
        for (int oc = 0; oc < 16; ++oc) acc[p][oc] = ws[288 + oc];

    #pragma unroll
    for (int ic = 0; ic < 2; ++ic)
        #pragma unroll
        for (int kh = 0; kh < 3; ++kh)
            #pragma unroll
            for (int kw = 0; kw < 3; ++kw) {
                float wv[16];
                #pragma unroll
                for (int oc = 0; oc < 16; ++oc) wv[oc] = ws[(oc * 18) + ic * 9 + kh * 3 + kw];
                #pragma unroll
                for (int p = 0; p < 4; ++p) {
                    float v = tile[ic][ly0 + p + kh][lx + kw];
                    #pragma unroll
                    for (int oc = 0; oc < 16; ++oc) acc[p][oc] = fmaf(v, wv[oc], acc[p][oc]);
                }
            }

    #pragma unroll
    for (int p = 0; p < 4; ++p) {
        int h = th0 + ly0 + p;
        #pragma unroll
        for (int oc = 0; oc < 16; ++oc) {
            out[((size_t)(b * 16 + oc) * 512 + h) * 512 + (tw0 + lx)] = acc[p][oc];
        }
    }
}

extern "C" void kernel_launch(void* const* d_in, const int* in_sizes, int n_in,
                              void* d_out, int out_size, void* d_ws, size_t ws_size,
                              hipStream_t stream) {
    const float* x   = (const float*)d_in[0];
    const float* hfw = (const float*)d_in[1];
    const float* lfw = (const float*)d_in[2];
    const float* cw  = (const float*)d_in[3];
    const float* cb  = (const float*)d_in[4];
    float* out = (float*)d_out;

    char* ws = (char*)d_ws;
    float* arr_raw      = (float*)(ws);                    // 16 MiB: 16 x 512 x 512
    float* a1           = (float*)(ws + 16777216);         //  4 MiB: 16 x 256 x 256
    float* a2           = (float*)(ws + 20971520);         //  1 MiB: 16 x 128 x 128
    unsigned int* maxbf = (unsigned int*)(ws + 22020096);  //  16 x 8 u32

    hipMemsetAsync(maxbf, 0, NB * 8 * sizeof(unsigned int), stream);
    k_dwt1<<<dim3(256, NB), 256, 0, stream>>>(x, arr_raw, a1, maxbf);
    k_dwt2<<<dim3(64, NB), 256, 0, stream>>>(a1, arr_raw, a2, maxbf);
    k_conv<<<dim3(8, 32, NB), 256, 0, stream>>>(arr_raw, a2, maxbf, hfw, lfw, cw, cb, out);
}

// Round 2
// 130.333 us; speedup vs baseline: 1.1748x; 1.1748x over previous
//
#include <hip/hip_runtime.h>

#define NB 16          // batch
#define NH 512
#define NW 512

// db2 decomposition filters
__device__ __constant__ float DLO[4] = {-0.12940952255092145f, 0.22414386804185735f, 0.836516303737469f, 0.48296291314469025f};
__device__ __constant__ float DHI[4] = {-0.48296291314469025f, 0.836516303737469f, -0.22414386804185735f, -0.12940952255092145f};

__device__ inline float wave_max(float v) {
    #pragma unroll
    for (int off = 32; off; off >>= 1) v = fmaxf(v, __shfl_xor(v, off, 64));
    return v;
}

// Level-1 DWT: x (512x512) -> a1 (256x256, scratch), ad1/da1/dd1 raw into arr_raw quadrants.
__global__ __launch_bounds__(256) void k_dwt1(const float* __restrict__ x,
                                              float* __restrict__ arr_raw,
                                              float* __restrict__ a1,
                                              unsigned int* __restrict__ maxbuf) {
    int b = blockIdx.y;
    int idx = blockIdx.x * 256 + threadIdx.x;
    int r = idx >> 8, c = idx & 255;
    const float* xb = x + (size_t)b * (NH * NW);

    float X[4][4];
    if (r >= 1 && c >= 1) {
        const float* p = xb + (2 * r - 2) * 512 + (2 * c - 2);
        #pragma unroll
        for (int k = 0; k < 4; ++k) {
            float2 u0 = *(const float2*)(p + k * 512);
            float2 u1 = *(const float2*)(p + k * 512 + 2);
            X[k][0] = u0.x; X[k][1] = u0.y; X[k][2] = u1.x; X[k][3] = u1.y;
        }
    } else {
        #pragma unroll
        for (int k = 0; k < 4; ++k) {
            int rr = (2 * r - 2 + k + 512) & 511;
            #pragma unroll
            for (int l = 0; l < 4; ++l) {
                int cc = (2 * c - 2 + l + 512) & 511;
                X[k][l] = xb[rr * 512 + cc];
            }
        }
    }
    // lo[l] here equals original lo[3-l]; second stage uses reversed taps so results match.
    float lo[4], hi[4];
    #pragma unroll
    for (int l = 0; l < 4; ++l) {
        float alo = 0.f, ahi = 0.f;
        #pragma unroll
        for (int k = 0; k < 4; ++k) { alo += DLO[3 - k] * X[k][l]; ahi += DHI[3 - k] * X[k][l]; }
        lo[l] = alo; hi[l] = ahi;
    }
    float va = 0.f, vad = 0.f, vda = 0.f, vdd = 0.f;
    #pragma unroll
    for (int l = 0; l < 4; ++l) {
        va  += DLO[3 - l] * lo[l];
        vad += DHI[3 - l] * lo[l];
        vda += DLO[3 - l] * hi[l];
        vdd += DHI[3 - l] * hi[l];
    }

    a1[b * 65536 + r * 256 + c] = va;
    float* arr = arr_raw + (size_t)b * (512 * 512);
    arr[r * 512 + (c + 256)]         = vad;  // top-right
    arr[(r + 256) * 512 + c]         = vda;  // bottom-left
    arr[(r + 256) * 512 + (c + 256)] = vdd;  // bottom-right

    // block max via wave shuffles + tiny LDS combine
    __shared__ float wmax[4][3];
    int wv = threadIdx.x >> 6, ln = threadIdx.x & 63;
    float m0 = wave_max(fabsf(vad));
    float m1 = wave_max(fabsf(vda));
    float m2 = wave_max(fabsf(vdd));
    if (ln == 0) { wmax[wv][0] = m0; wmax[wv][1] = m1; wmax[wv][2] = m2; }
    __syncthreads();
    if (threadIdx.x < 3) {
        int i = threadIdx.x;
        float m = fmaxf(fmaxf(wmax[0][i], wmax[1][i]), fmaxf(wmax[2][i], wmax[3][i]));
        atomicMax(maxbuf + b * 8 + i, __float_as_uint(m));
    }
}

// Level-2 DWT: a1 (256x256) -> a2 raw (top-left 128x128 of arr_raw + scratch), ad2/da2/dd2 raw.
__global__ __launch_bounds__(256) void k_dwt2(const float* __restrict__ a1,
                                              float* __restrict__ arr_raw,
                                              float* __restrict__ a2,
                                              unsigned int* __restrict__ maxbuf) {
    int b = blockIdx.y;
    int idx = blockIdx.x * 256 + threadIdx.x;
    int r = idx >> 7, c = idx & 127;
    const float* ab = a1 + b * 65536;

    float X[4][4];
    if (r >= 1 && c >= 1) {
        const float* p = ab + (2 * r - 2) * 256 + (2 * c - 2);
        #pragma unroll
        for (int k = 0; k < 4; ++k) {
            float2 u0 = *(const float2*)(p + k * 256);
            float2 u1 = *(const float2*)(p + k * 256 + 2);
            X[k][0] = u0.x; X[k][1] = u0.y; X[k][2] = u1.x; X[k][3] = u1.y;
        }
    } else {
        #pragma unroll
        for (int k = 0; k < 4; ++k) {
            int rr = (2 * r - 2 + k + 256) & 255;
            #pragma unroll
            for (int l = 0; l < 4; ++l) {
                int cc = (2 * c - 2 + l + 256) & 255;
                X[k][l] = ab[rr * 256 + cc];
            }
        }
    }
    float lo[4], hi[4];
    #pragma unroll
    for (int l = 0; l < 4; ++l) {
        float alo = 0.f, ahi = 0.f;
        #pragma unroll
        for (int k = 0; k < 4; ++k) { alo += DLO[3 - k] * X[k][l]; ahi += DHI[3 - k] * X[k][l]; }
        lo[l] = alo; hi[l] = ahi;
    }
    float va = 0.f, vad = 0.f, vda = 0.f, vdd = 0.f;
    #pragma unroll
    for (int l = 0; l < 4; ++l) {
        va  += DLO[3 - l] * lo[l];
        vad += DHI[3 - l] * lo[l];
        vda += DLO[3 - l] * hi[l];
        vdd += DHI[3 - l] * hi[l];
    }

    a2[b * 16384 + r * 128 + c] = va;
    float* arr = arr_raw + (size_t)b * (512 * 512);
    arr[r * 512 + c]                 = va;   // raw a2 in final position
    arr[r * 512 + (c + 128)]         = vad;
    arr[(r + 128) * 512 + c]         = vda;
    arr[(r + 128) * 512 + (c + 128)] = vdd;

    __shared__ float wmax[4][4];
    int wv = threadIdx.x >> 6, ln = threadIdx.x & 63;
    float m0 = wave_max(fabsf(va));
    float m1 = wave_max(fabsf(vad));
    float m2 = wave_max(fabsf(vda));
    float m3 = wave_max(fabsf(vdd));
    if (ln == 0) { wmax[wv][0] = m0; wmax[wv][1] = m1; wmax[wv][2] = m2; wmax[wv][3] = m3; }
    __syncthreads();
    if (threadIdx.x < 4) {
        int i = threadIdx.x;
        float m = fmaxf(fmaxf(wmax[0][i], wmax[1][i]), fmaxf(wmax[2][i], wmax[3][i]));
        atomicMax(maxbuf + b * 8 + 3 + i, __float_as_uint(m));
    }
}

// Fused: normalize+assemble (ch0), bilinear low branch (ch1), 3x3 conv 2->16, +bias.
// Tile 128w x 4h per 256-thread block. tid>>6 selects a 4-oc group (weights in regs);
// each lane handles two 4-wide px quads (rows rp, rp+2). 8 x dwordx4 stores/thread.
__global__ __launch_bounds__(256) void k_conv(const float* __restrict__ arr_raw,
                                              const float* __restrict__ a2,
                                              const unsigned int* __restrict__ maxbuf,
                                              const float* __restrict__ hfw,
                                              const float* __restrict__ lfw,
                                              const float* __restrict__ cw,
                                              const float* __restrict__ cb,
                                              float* __restrict__ out) {
    int b   = blockIdx.z;
    int th0 = blockIdx.y * 4;
    int tw0 = blockIdx.x * 128;
    int tid = threadIdx.x;
    int ocg  = tid >> 6;
    int lane = tid & 63;

    __shared__ __align__(16) float tile[2][6][132];

    // per-thread weights: oc in [ocg*4, ocg*4+4), layout cw[oc][ic][kh][kw]
    float wreg[72], breg[4];
    {
        const float4* wp = (const float4*)(cw + ocg * 72);   // 288B-aligned
        #pragma unroll
        for (int i = 0; i < 18; ++i) {
            float4 t = wp[i];
            wreg[4 * i] = t.x; wreg[4 * i + 1] = t.y; wreg[4 * i + 2] = t.z; wreg[4 * i + 3] = t.w;
        }
        #pragma unroll
        for (int o = 0; o < 4; ++o) breg[o] = cb[ocg * 4 + o];
    }

    const unsigned int* mb = maxbuf + b * 8;
    float inv_ad1 = 1.f / __uint_as_float(mb[0]);
    float inv_da1 = 1.f / __uint_as_float(mb[1]);
    float inv_dd1 = 1.f / __uint_as_float(mb[2]);
    float inv_a2  = 1.f / __uint_as_float(mb[3]);
    float inv_ad2 = 1.f / __uint_as_float(mb[4]);
    float inv_da2 = 1.f / __uint_as_float(mb[5]);
    float inv_dd2 = 1.f / __uint_as_float(mb[6]);

    const float* arr = arr_raw + (size_t)b * (512 * 512);
    const float* a2b = a2 + b * 16384;

    for (int i = tid; i < 6 * 130; i += 256) {
        int row = i / 130;
        int col = i - row * 130;
        int gh = th0 + row - 1;
        int gw = tw0 + col - 1;
        float v0 = 0.f, v1 = 0.f;
        if (gh >= 0 && gh < 512 && gw >= 0 && gw < 512) {
            // channel 0: normalized quad-tree * hfw
            float raw = arr[gh * 512 + gw];
            float inv;
            if (gh < 256) {
                if (gw < 256) {
                    if (gh < 128) inv = (gw < 128) ? inv_a2 : inv_ad2;
                    else          inv = (gw < 128) ? inv_da2 : inv_dd2;
                } else inv = inv_ad1;
            } else inv = (gw < 256) ? inv_da1 : inv_dd1;
            v0 = raw * inv * hfw[gh * 512 + gw];

            // channel 1: bilinear upsample of norm(a2)*lfw (half-pixel, clip)
            float sh = fminf(fmaxf(0.25f * (float)gh - 0.375f, 0.f), 127.f);
            float sw = fminf(fmaxf(0.25f * (float)gw - 0.375f, 0.f), 127.f);
            int r0 = (int)sh; float fr = sh - (float)r0; int r1 = min(r0 + 1, 127);
            int c0 = (int)sw; float fc = sw - (float)c0; int c1 = min(c0 + 1, 127);
            float g00 = a2b[r0 * 128 + c0] * inv_a2 * lfw[r0 * 128 + c0];
            float g01 = a2b[r0 * 128 + c1] * inv_a2 * lfw[r0 * 128 + c1];
            float g10 = a2b[r1 * 128 + c0] * inv_a2 * lfw[r1 * 128 + c0];
            float g11 = a2b[r1 * 128 + c1] * inv_a2 * lfw[r1 * 128 + c1];
            float t0 = g00 * (1.f - fr) + g10 * fr;   // rows first (matches ref order)
            float t1 = g01 * (1.f - fr) + g11 * fr;
            v1 = t0 * (1.f - fc) + t1 * fc;
        }
        tile[0][row][col] = v0;
        tile[1][row][col] = v1;
    }
    __syncthreads();

    int wq = lane & 31;   // w-quad: w0 = 4*wq
    int rp = lane >> 5;   // rows rp and rp+2

    float acc[4][8];      // [oc][2 rows x 4 px]
    #pragma unroll
    for (int o = 0; o < 4; ++o)
        #pragma unroll
        for (int j = 0; j < 8; ++j) acc[o][j] = breg[o];

    #pragma unroll
    for (int ic = 0; ic < 2; ++ic)
        #pragma unroll
        for (int kh = 0; kh < 3; ++kh) {
            const float* r0p = &tile[ic][rp + kh][4 * wq];
            const float* r1p = &tile[ic][rp + 2 + kh][4 * wq];
            float v[6], u[6];
            { float4 t = *(const float4*)r0p; v[0] = t.x; v[1] = t.y; v[2] = t.z; v[3] = t.w;
              float2 s = *(const float2*)(r0p + 4); v[4] = s.x; v[5] = s.y; }
            { float4 t = *(const float4*)r1p; u[0] = t.x; u[1] = t.y; u[2] = t.z; u[3] = t.w;
              float2 s = *(const float2*)(r1p + 4); u[4] = s.x; u[5] = s.y; }
            #pragma unroll
            for (int kw = 0; kw < 3; ++kw)
                #pragma unroll
                for (int o = 0; o < 4; ++o) {
                    float wv = wreg[o * 18 + ic * 9 + kh * 3 + kw];
                    #pragma unroll
                    for (int j = 0; j < 4; ++j) {
                        acc[o][j]     = fmaf(v[j + kw], wv, acc[o][j]);
                        acc[o][4 + j] = fmaf(u[j + kw], wv, acc[o][4 + j]);
                    }
                }
        }

    size_t ob = (size_t)(b * 16 + ocg * 4) * 512 * 512;
    #pragma unroll
    for (int o = 0; o < 4; ++o) {
        #pragma unroll
        for (int h = 0; h < 2; ++h) {
            int row = rp + 2 * h;
            float4 val = make_float4(acc[o][4 * h], acc[o][4 * h + 1], acc[o][4 * h + 2], acc[o][4 * h + 3]);
            *(float4*)(out + ob + (size_t)o * 512 * 512 + (size_t)(th0 + row) * 512 + tw0 + 4 * wq) = val;
        }
    }
}

extern "C" void kernel_launch(void* const* d_in, const int* in_sizes, int n_in,
                              void* d_out, int out_size, void* d_ws, size_t ws_size,
                              hipStream_t stream) {
    const float* x   = (const float*)d_in[0];
    const float* hfw = (const float*)d_in[1];
    const float* lfw = (const float*)d_in[2];
    const float* cw  = (const float*)d_in[3];
    const float* cb  = (const float*)d_in[4];
    float* out = (float*)d_out;

    char* ws = (char*)d_ws;
    float* arr_raw      = (float*)(ws);                    // 16 MiB: 16 x 512 x 512
    float* a1           = (float*)(ws + 16777216);         //  4 MiB: 16 x 256 x 256
    float* a2           = (float*)(ws + 20971520);         //  1 MiB: 16 x 128 x 128
    unsigned int* maxbf = (unsigned int*)(ws + 22020096);  //  16 x 8 u32

    hipMemsetAsync(maxbf, 0, NB * 8 * sizeof(unsigned int), stream);
    k_dwt1<<<dim3(256, NB), 256, 0, stream>>>(x, arr_raw, a1, maxbf);
    k_dwt2<<<dim3(64, NB), 256, 0, stream>>>(a1, arr_raw, a2, maxbf);
    k_conv<<<dim3(4, 128, NB), 256, 0, stream>>>(arr_raw, a2, maxbf, hfw, lfw, cw, cb, out);
}